// Round 2
// baseline (93.143 us; speedup 1.0000x reference)
//
#include <hip/hip_runtime.h>

// mask[b, i, j] = (i < len_q[b]) & (j < len_k[b]);  out is int32 (0 / 1)
// B=32, SEQ=2048  ->  out_size = 32*2048*2048 = 134,217,728 ints (512 MiB)

constexpr int SEQ = 2048;

__global__ __launch_bounds__(256) void padmask_kernel(
        const int* __restrict__ len_q,
        const int* __restrict__ len_k,
        int* __restrict__ out) {
    const int row = blockIdx.x;        // row = b*SEQ + i
    const int b   = row >> 11;         // / 2048
    const int i   = row & (SEQ - 1);

    const int lq = len_q[b];
    const int lk = len_k[b];
    const bool qv = (i < lq);

    int4* out4 = reinterpret_cast<int4*>(out + (size_t)row * SEQ);
    const int t = threadIdx.x;

    #pragma unroll
    for (int it = 0; it < 2; ++it) {
        const int idx4 = t + it * 256;     // int4 index within the row
        const int j = idx4 * 4;
        int4 v;
        v.x = (qv && (j + 0) < lk) ? 1 : 0;
        v.y = (qv && (j + 1) < lk) ? 1 : 0;
        v.z = (qv && (j + 2) < lk) ? 1 : 0;
        v.w = (qv && (j + 3) < lk) ? 1 : 0;
        out4[idx4] = v;
    }
}

extern "C" void kernel_launch(void* const* d_in, const int* in_sizes, int n_in,
                              void* d_out, int out_size, void* d_ws, size_t ws_size,
                              hipStream_t stream) {
    const int* len_q = (const int*)d_in[0];
    const int* len_k = (const int*)d_in[1];
    int* out = (int*)d_out;

    const int batch = in_sizes[0];            // 32
    const int n_rows = batch * SEQ;           // 65536 blocks

    padmask_kernel<<<n_rows, 256, 0, stream>>>(len_q, len_k, out);
}